// Round 5
// baseline (103.487 us; speedup 1.0000x reference)
//
#include <hip/hip_runtime.h>

#define GAT_ALPHA 0.2f
#define INV_N (1.0f / 2048.0f)

typedef float f32x4 __attribute__((ext_vector_type(4)));
typedef int   i32x4 __attribute__((ext_vector_type(4)));
typedef __bf16 bf16x8 __attribute__((ext_vector_type(8)));
typedef unsigned short us8 __attribute__((ext_vector_type(8)));

__device__ __forceinline__ unsigned short f2bf(float x) {
  union { float f; unsigned u; } v; v.f = x;
  unsigned r = v.u + 0x7FFFu + ((v.u >> 16) & 1u);   // RNE
  return (unsigned short)(r >> 16);
}
__device__ __forceinline__ float lrelu(float x) {
  return fmaxf(x, 0.f) + GAT_ALPHA * fminf(x, 0.f);
}

// ---------------- k0: Wh = h @ W (f32), s1/s2, WhT in bf16 [b][f][j] ----------------
__global__ __launch_bounds__(256)
void k0_wh(const float* __restrict__ h, const float* __restrict__ W,
           const float* __restrict__ a, unsigned short* __restrict__ WhT,
           float* __restrict__ s1g, float* __restrict__ s2g)
{
  __shared__ float h_s[64][132];
  __shared__ float W_s[128][64];
  __shared__ float wt_s[64][66];
  __shared__ float a_s[128];
  const int t = threadIdx.x;
  const int b = blockIdx.y;
  const int r0 = blockIdx.x * 64;

#pragma unroll
  for (int v = 0; v < 8; ++v) {
    int c = v * 256 + t;
    int k = c >> 4, fo = (c & 15) << 2;
    *(float4*)&W_s[k][fo] = *(const float4*)&W[k * 64 + fo];
  }
#pragma unroll
  for (int v = 0; v < 8; ++v) {
    int c = v * 256 + t;
    int r = c >> 5, ko = (c & 31) << 2;
    *(float4*)&h_s[r][ko] = *(const float4*)&h[((size_t)(b * 2048 + r0 + r)) * 128 + ko];
  }
  if (t < 128) a_s[t] = a[t];
  __syncthreads();

  const int tg = t >> 4;          // 0..15
  const int tf = (t & 15) << 2;   // f base
  float acc[4][4] = {};
#pragma unroll
  for (int k4 = 0; k4 < 32; ++k4) {
    float4 hv[4];
#pragma unroll
    for (int i = 0; i < 4; ++i)
      hv[i] = *(const float4*)&h_s[i * 16 + tg][k4 * 4];
#pragma unroll
    for (int kk = 0; kk < 4; ++kk) {
      float4 wv = *(const float4*)&W_s[k4 * 4 + kk][tf];
#pragma unroll
      for (int i = 0; i < 4; ++i) {
        float hx = ((const float*)&hv[i])[kk];
        acc[i][0] = fmaf(hx, wv.x, acc[i][0]);
        acc[i][1] = fmaf(hx, wv.y, acc[i][1]);
        acc[i][2] = fmaf(hx, wv.z, acc[i][2]);
        acc[i][3] = fmaf(hx, wv.w, acc[i][3]);
      }
    }
  }
#pragma unroll
  for (int i = 0; i < 4; ++i)
#pragma unroll
    for (int j = 0; j < 4; ++j)
      wt_s[tf + j][i * 16 + tg] = acc[i][j];
  __syncthreads();

  if (t < 64) {   // s1/s2 for row r = t (f32 exact)
    float v1 = 0.f, v2 = 0.f;
#pragma unroll 8
    for (int f = 0; f < 64; ++f) {
      float w = wt_s[f][t];
      v1 = fmaf(w, a_s[f], v1);
      v2 = fmaf(w, a_s[64 + f], v2);
    }
    s1g[b * 2048 + r0 + t] = v1;
    s2g[b * 2048 + r0 + t] = v2;
  }
  {  // WhT bf16 write, [b][f][j]
    int f = t >> 2, rb = (t & 3) << 4;
    unsigned short pk[16];
#pragma unroll
    for (int i = 0; i < 16; ++i) pk[i] = f2bf(wt_s[f][rb + i]);
    size_t base = ((size_t)(b * 64 + f)) * 2048 + r0 + rb;
    *(uint4*)&WhT[base]     = *(uint4*)&pk[0];
    *(uint4*)&WhT[base + 8] = *(uint4*)&pk[8];
  }
}

// ---------------- k1: wave-per-row: denom l + bitmask (ballot); no max pass ----------------
// bit convention: word[c*4 + q] bit l  <->  j = c*256 + 4*l + q
__global__ __launch_bounds__(256)
void k1_stats(const int* __restrict__ adj, const float* __restrict__ s1g,
              const float* __restrict__ s2g, float* __restrict__ lrow,
              unsigned long long* __restrict__ gmask)
{
  const int t = threadIdx.x;
  const int l = t & 63, w = t >> 6;
  const int b = blockIdx.y;
  const int i = blockIdx.x * 4 + w;
  const size_t row = (size_t)(b * 2048 + i);
  const int* __restrict__ arow = adj + row * 2048;
  const float* __restrict__ z = s2g + b * 2048;
  unsigned long long* __restrict__ g = gmask + row * 32;

  float4 zv[8];
  unsigned pb = 0;           // 4 pred bits per chunk, 8 chunks
#pragma unroll
  for (int c = 0; c < 8; ++c) {
    i32x4 av = __builtin_nontemporal_load((const i32x4*)&arow[c * 256 + 4 * l]);
    zv[c] = *(const float4*)&z[c * 256 + 4 * l];
    const bool p0 = av.x > 0, p1 = av.y > 0, p2 = av.z > 0, p3 = av.w > 0;
    unsigned long long b0 = __ballot(p0), b1 = __ballot(p1);
    unsigned long long b2 = __ballot(p2), b3 = __ballot(p3);
    if (l == 0) {
      ulonglong2 u0; u0.x = b0; u0.y = b1;
      ulonglong2 u1; u1.x = b2; u1.y = b3;
      *(ulonglong2*)&g[c * 4]     = u0;
      *(ulonglong2*)&g[c * 4 + 2] = u1;
    }
    pb |= (unsigned(p0) | (unsigned(p1) << 1) | (unsigned(p2) << 2) | (unsigned(p3) << 3)) << (c * 4);
  }

  const float s1v = s1g[row];
  float sum = 0.f;
#pragma unroll
  for (int c = 0; c < 8; ++c) {
    sum += ((pb >> (c * 4)) & 1u) ? __expf(lrelu(s1v + zv[c].x)) : 0.f;
    sum += ((pb >> (c * 4 + 1)) & 1u) ? __expf(lrelu(s1v + zv[c].y)) : 0.f;
    sum += ((pb >> (c * 4 + 2)) & 1u) ? __expf(lrelu(s1v + zv[c].z)) : 0.f;
    sum += ((pb >> (c * 4 + 3)) & 1u) ? __expf(lrelu(s1v + zv[c].w)) : 0.f;
  }
#pragma unroll
  for (int o = 32; o > 0; o >>= 1) sum += __shfl_xor(sum, o);

  if (l == 0) lrow[row] = sum;
}

// ---------------- k2: barrier-free att write + partial PV MFMA (j-split 2-way) ----------------
// 32 rows/block, 4 waves. Wave w: row-tile rt=(w&1)*16, f-tiles 2*(w>>1), +1.
// Each lane computes ITS OWN MFMA A-fragment in registers:
//   row = rt + (l&15), j = j0 + ks*32 + (l>>4)*8 + m   (m = 0..7)
// B-fragments load straight from L2-resident WhT (issued early, T14).
// No LDS tiles, no loop barriers. Partial acc -> pp[jh]; k3 adds + ELU.
__global__ __launch_bounds__(256)
void k2_att_pv(const unsigned long long* __restrict__ gmask,
               const unsigned short* __restrict__ WhT,
               const float* __restrict__ s1g, const float* __restrict__ s2g,
               const float* __restrict__ lrow,
               float* __restrict__ pp0, float* __restrict__ pp1,
               float* __restrict__ att)
{
  __shared__ float z_s[2048];
  __shared__ float s1_s[32], il_s[32];

  const int t = threadIdx.x;
  const int b = blockIdx.z;
  const int jh = blockIdx.y;
  const int jb0 = jh << 10;
  const int r0 = blockIdx.x * 32;
  const size_t rowb = (size_t)(b * 2048 + r0);

  *(float4*)&z_s[t * 8]     = *(const float4*)&s2g[b * 2048 + t * 8];
  *(float4*)&z_s[t * 8 + 4] = *(const float4*)&s2g[b * 2048 + t * 8 + 4];
  if (t < 32) {
    float L = lrow[rowb + t];
    s1_s[t] = s1g[rowb + t];
    il_s[t] = (L > 0.f) ? 1.f / L : -1.f;   // -1 sentinel: no neighbors -> uniform 1/N
  }
  __syncthreads();

  const int w  = t >> 6, l = t & 63;
  const int ln = l & 15, lg = l >> 4;
  const int rt = (w & 1) << 4;
  const int fp = w >> 1;                    // f-tile pair: tiles 2fp, 2fp+1
  const int row = rt + ln;
  const bool writer = (w < 2);

  const float s1v = s1_s[row];
  const float il  = il_s[row];
  const bool uni  = (il < 0.f);
  const unsigned long long* __restrict__ gm = gmask + (rowb + row) * 32;
  const unsigned short* __restrict__ wb0 = WhT + ((size_t)(b * 64 + 2 * fp * 16 + ln)) * 2048;
  const unsigned short* __restrict__ wb1 = wb0 + 16 * 2048;
  float* __restrict__ arow = att + (rowb + row) * 2048;

  f32x4 acc0 = {0.f, 0.f, 0.f, 0.f};
  f32x4 acc1 = {0.f, 0.f, 0.f, 0.f};

  unsigned long long w0 = 0, w1 = 0, w2 = 0, w3 = 0;
  for (int j0 = jb0; j0 < jb0 + 1024; j0 += 128) {
    // T14: issue all B-fragment loads for this j0-iter up front
    us8 breg0[4], breg1[4];
#pragma unroll
    for (int ks = 0; ks < 4; ++ks) {
      const int jb = j0 + ks * 32 + lg * 8;
      breg0[ks] = *(const us8*)&wb0[jb];
      breg1[ks] = *(const us8*)&wb1[jb];
    }
    if ((j0 & 255) == jb0 % 256) {  // refresh ballot words per 256-j chunk
      const int c = j0 >> 8;
      ulonglong2 u0 = *(const ulonglong2*)&gm[c * 4];
      ulonglong2 u1 = *(const ulonglong2*)&gm[c * 4 + 2];
      w0 = u0.x; w1 = u0.y; w2 = u1.x; w3 = u1.y;
    }
#pragma unroll
    for (int ks = 0; ks < 4; ++ks) {
      const int jb = j0 + ks * 32 + lg * 8;
      const int pos0 = (jb & 255) >> 2;     // base bit position, never wraps
      const float4 za = *(const float4*)&z_s[jb];
      const float4 zb = *(const float4*)&z_s[jb + 4];
      float o[8];
#define PE(dst, zz, m)                                                     \
      { float e = __expf(lrelu(s1v + (zz))) * il;                          \
        const unsigned long long wq = ((m) & 3) == 0 ? w0 :                \
                                      ((m) & 3) == 1 ? w1 :                \
                                      ((m) & 3) == 2 ? w2 : w3;            \
        const bool on = ((wq >> (pos0 + ((m) >> 2))) & 1ull) != 0;         \
        dst = uni ? INV_N : (on ? e : 0.f); }
      PE(o[0], za.x, 0) PE(o[1], za.y, 1) PE(o[2], za.z, 2) PE(o[3], za.w, 3)
      PE(o[4], zb.x, 4) PE(o[5], zb.y, 5) PE(o[6], zb.z, 6) PE(o[7], zb.w, 7)
#undef PE
      if (writer) {
        f32x4 sa = {o[0], o[1], o[2], o[3]};
        f32x4 sb = {o[4], o[5], o[6], o[7]};
        __builtin_nontemporal_store(sa, (f32x4*)&arow[jb]);
        __builtin_nontemporal_store(sb, (f32x4*)&arow[jb + 4]);
      }
      bf16x8 af;
#pragma unroll
      for (int m = 0; m < 8; ++m) af[m] = (__bf16)o[m];
      union { us8 u; bf16x8 v; } b0c, b1c;
      b0c.u = breg0[ks];
      b1c.u = breg1[ks];
      acc0 = __builtin_amdgcn_mfma_f32_16x16x32_bf16(af, b0c.v, acc0, 0, 0, 0);
      acc1 = __builtin_amdgcn_mfma_f32_16x16x32_bf16(af, b1c.v, acc1, 0, 0, 0);
    }
  }

  // partial write. C/D layout: col(N=f)=lane&15, row(M)=4*(lane>>4)+reg
  float* __restrict__ pp = (jh == 0) ? pp0 : pp1;
#pragma unroll
  for (int q = 0; q < 4; ++q) {
    const int rr = rt + lg * 4 + q;
    pp[(rowb + rr) * 64 + (2 * fp) * 16 + ln]     = acc0[q];
    pp[(rowb + rr) * 64 + (2 * fp + 1) * 16 + ln] = acc1[q];
  }
}

// ---------------- k3: hout = elu(pp0 + pp1) ----------------
__global__ __launch_bounds__(256)
void k3_elu(const float* __restrict__ pp0, const float* __restrict__ pp1,
            float* __restrict__ hout)
{
  const size_t idx = ((size_t)blockIdx.x * 256 + threadIdx.x) * 4;
  float4 a = *(const float4*)&pp0[idx];
  float4 c = *(const float4*)&pp1[idx];
  float4 o;
  float x;
  x = a.x + c.x; o.x = (x > 0.f) ? x : expm1f(x);
  x = a.y + c.y; o.y = (x > 0.f) ? x : expm1f(x);
  x = a.z + c.z; o.z = (x > 0.f) ? x : expm1f(x);
  x = a.w + c.w; o.w = (x > 0.f) ? x : expm1f(x);
  *(float4*)&hout[idx] = o;
}

extern "C" void kernel_launch(void* const* d_in, const int* in_sizes, int n_in,
                              void* d_out, int out_size, void* d_ws, size_t ws_size,
                              hipStream_t stream)
{
  const float* h   = (const float*)d_in[0];
  const int*   adj = (const int*)d_in[1];
  const float* W   = (const float*)d_in[2];
  const float* a   = (const float*)d_in[3];
  float* hout = (float*)d_out;
  float* att  = hout + (size_t)8 * 2048 * 64;

  char* ws = (char*)d_ws;
  unsigned short* WhT = (unsigned short*)ws;                    // 2 MB
  float* s1 = (float*)(ws + (size_t)(2u << 20));                // 64 KB each
  float* s2 = s1 + 16384;
  float* lr = s2 + 16384;
  unsigned long long* gmask =
      (unsigned long long*)(ws + (size_t)(2u << 20) + 3 * 65536); // 4 MB
  float* pp0 = (float*)(ws + (size_t)(2u << 20) + 3 * 65536 + (4u << 20)); // 4 MB
  float* pp1 = pp0 + (size_t)8 * 2048 * 64;                                // 4 MB

  k0_wh    <<<dim3(32, 8),    256, 0, stream>>>(h, W, a, WhT, s1, s2);
  k1_stats <<<dim3(512, 8),   256, 0, stream>>>(adj, s1, s2, lr, gmask);
  k2_att_pv<<<dim3(64, 2, 8), 256, 0, stream>>>(gmask, WhT, s1, s2, lr, pp0, pp1, att);
  k3_elu   <<<dim3(1024),     256, 0, stream>>>(pp0, pp1, hout);
}